// Round 8
// baseline (232.403 us; speedup 1.0000x reference)
//
#include <hip/hip_runtime.h>
#include <hip/hip_bf16.h>
#include <cstdint>

// Workspace layout (bytes):
//   [0,        8388608)  xb   : x as bf16 [4096][1024]   (aliased later as ao)
//   [8388608, 14680064)  wqkvT: w_qkv^T bf16 [3072][1024]
//   [14680064,16777216)  wprojT: w_proj^T bf16 [1024][1024]
//   [16777216,25165824)  qb   : q (rope'd, *SCALE*log2e) bf16 [16][4096][64]
//   [25165824,33554432)  kb   : k (rope'd) bf16 [16][4096][64]
//   [33554432,41943040)  vT   : v^T bf16 [16][64][4096]
//   ao (attention out bf16 [4096][1024]) aliases xb.

#define TOK 4096
#define DIM_ 1024
#define NHEAD 16
#define HDIM 64
#define N3 3072
#define SCALE_LOG2E 0.18033688011112042f  // (1/8) * log2(e)

typedef __bf16 bf16_t;
typedef bf16_t bf16x8 __attribute__((ext_vector_type(8)));
typedef float floatx4 __attribute__((ext_vector_type(4)));
typedef float floatx16 __attribute__((ext_vector_type(16)));

__device__ __forceinline__ void async_ld16(const bf16_t* g, bf16_t* l) {
  __builtin_amdgcn_global_load_lds(
      (const __attribute__((address_space(1))) void*)(g),
      (__attribute__((address_space(3))) void*)(l), 16, 0, 0);
}

__device__ __forceinline__ uint32_t pkbf(float a, float b) {
  union { bf16_t h[2]; uint32_t u; } x;
  x.h[0] = (bf16_t)a; x.h[1] = (bf16_t)b;
  return x.u;
}

// ---------------- fused prep: cvt x -> bf16; transpose+cvt w_qkv, w_proj ----
// blocks [0,4096): xb; [4096,7168): wqkvT; [7168,8192): wprojT
__global__ __launch_bounds__(256) void k_prep(
    const float* __restrict__ x, const float* __restrict__ w_qkv,
    const float* __restrict__ w_proj, bf16_t* __restrict__ xb,
    bf16_t* __restrict__ wqkvT, bf16_t* __restrict__ wprojT) {
  __shared__ float tile[32][33];
  const int b = blockIdx.x;
  if (b < 4096) {
    int i = b * 256 + threadIdx.x;
    float4 v = ((const float4*)x)[i];
    union { bf16_t bb[4]; uint64_t u; } p;
    p.bb[0] = (bf16_t)v.x; p.bb[1] = (bf16_t)v.y;
    p.bb[2] = (bf16_t)v.z; p.bb[3] = (bf16_t)v.w;
    ((uint64_t*)xb)[i] = p.u;
    return;
  }
  const float* in; bf16_t* out; int R, C, c0, r0;
  if (b < 7168) {
    int bb = b - 4096; in = w_qkv; out = wqkvT; R = 1024; C = 3072;
    c0 = (bb % 96) * 32; r0 = (bb / 96) * 32;
  } else {
    int bb = b - 7168; in = w_proj; out = wprojT; R = 1024; C = 1024;
    c0 = (bb % 32) * 32; r0 = (bb / 32) * 32;
  }
  int tx = threadIdx.x & 31, ty = threadIdx.x >> 5;
#pragma unroll
  for (int i = 0; i < 4; i++) {
    int r = ty + i * 8;
    tile[r][tx] = in[(size_t)(r0 + r) * C + c0 + tx];
  }
  __syncthreads();
#pragma unroll
  for (int i = 0; i < 4; i++) {
    int c = ty + i * 8;
    out[(size_t)(c0 + c) * R + r0 + tx] = (bf16_t)tile[tx][c];
  }
}

// ---------------- QKV GEMM + bias + RoPE + scatter ----------------
__global__ __launch_bounds__(256) void k_qkv(
    const bf16_t* __restrict__ A,   // [4096][1024]
    const bf16_t* __restrict__ Bt,  // [3072][1024]
    const float* __restrict__ bias, // [3072]
    const float* __restrict__ cs,   // [4096][32]
    const float* __restrict__ sn,   // [4096][32]
    bf16_t* __restrict__ qb, bf16_t* __restrict__ kb, bf16_t* __restrict__ vT) {
  constexpr int K = 1024, BK = 32;
  __shared__ bf16_t As[128 * BK] __attribute__((aligned(16)));
  __shared__ bf16_t Bs[128 * BK] __attribute__((aligned(16)));
  const int t = threadIdx.x;
  const int lane = t & 63, w = t >> 6;
  const int lrow = lane & 15, quad = lane >> 4;
  const int m0 = blockIdx.y * 128, n0 = blockIdx.x * 128;
  const int wm = (w >> 1) * 64, wn = (w & 1) * 64;

  const floatx4 ZV = {0.f, 0.f, 0.f, 0.f};
  floatx4 acc[4][4];
#pragma unroll
  for (int i = 0; i < 4; i++)
#pragma unroll
    for (int j = 0; j < 4; j++) acc[i][j] = ZV;

  for (int kt = 0; kt < K; kt += BK) {
#pragma unroll
    for (int r = 0; r < 2; r++) {
      int idx = r * 256 + t;
      int lbase = (r * 256 + w * 64) * 8;
      async_ld16(&A[(size_t)(m0 + (idx >> 2)) * K + kt + (idx & 3) * 8], &As[lbase]);
      async_ld16(&Bt[(size_t)(n0 + (idx >> 2)) * K + kt + (idx & 3) * 8], &Bs[lbase]);
    }
    __syncthreads();
    bf16x8 af[4], bf[4];
#pragma unroll
    for (int i = 0; i < 4; i++)
      af[i] = *(const bf16x8*)&As[(wm + i * 16 + lrow) * BK + quad * 8];
#pragma unroll
    for (int i = 0; i < 4; i++)
      bf[i] = *(const bf16x8*)&Bs[(wn + i * 16 + lrow) * BK + quad * 8];
#pragma unroll
    for (int mi = 0; mi < 4; mi++)
#pragma unroll
      for (int ni = 0; ni < 4; ni++)
        acc[mi][ni] = __builtin_amdgcn_mfma_f32_16x16x32_bf16(af[mi], bf[ni], acc[mi][ni], 0, 0, 0);
    __syncthreads();
  }

  // Epilogue: wave covers cols [c0, c0+64) = exactly one head of one of q/k/v.
  const int c0 = n0 + wn;
  const int seg = c0 >> 10;           // 0=q 1=k 2=v
  const int h = (c0 & 1023) >> 6;
  float bv[4];
#pragma unroll
  for (int ni = 0; ni < 4; ni++) bv[ni] = bias[c0 + ni * 16 + lrow];

  if (seg < 2) {
    bf16_t* base = ((seg == 0) ? qb : kb) + (size_t)h * TOK * HDIM;
    const float qs = (seg == 0) ? SCALE_LOG2E : 1.0f;
#pragma unroll
    for (int mi = 0; mi < 4; mi++) {
#pragma unroll
      for (int reg = 0; reg < 4; reg++) {
        const int r = m0 + wm + mi * 16 + quad * 4 + reg;
        const float c_lo = cs[r * 32 + lrow];
        const float c_hi = cs[r * 32 + 16 + lrow];
        const float s_lo = sn[r * 32 + lrow];
        const float s_hi = sn[r * 32 + 16 + lrow];
        const float v0 = acc[mi][0][reg] + bv[0];
        const float v1 = acc[mi][1][reg] + bv[1];
        const float v2 = acc[mi][2][reg] + bv[2];
        const float v3 = acc[mi][3][reg] + bv[3];
        // RoPE: d<32: v*cos - v[d+32]*sin ; d>=32: v*cos + v[d-32]*sin
        const float o0 = (v0 * c_lo - v2 * s_lo) * qs;
        const float o1 = (v1 * c_hi - v3 * s_hi) * qs;
        const float o2 = (v2 * c_lo + v0 * s_lo) * qs;
        const float o3 = (v3 * c_hi + v1 * s_hi) * qs;
        bf16_t* rp = base + (size_t)r * HDIM + lrow;
        rp[0]  = (bf16_t)o0;
        rp[16] = (bf16_t)o1;
        rp[32] = (bf16_t)o2;
        rp[48] = (bf16_t)o3;
      }
    }
  } else {
    // V: store transposed [h][d][n]; 4 acc regs = 4 consecutive rows -> 8B store
    bf16_t* base = vT + (size_t)h * HDIM * TOK;
#pragma unroll
    for (int mi = 0; mi < 4; mi++) {
      const int rbase = m0 + wm + mi * 16 + quad * 4;
#pragma unroll
      for (int ni = 0; ni < 4; ni++) {
        union { bf16_t b[4]; uint64_t u; } p;
#pragma unroll
        for (int reg = 0; reg < 4; reg++) p.b[reg] = (bf16_t)(acc[mi][ni][reg] + bv[ni]);
        *(uint64_t*)&base[(size_t)(ni * 16 + lrow) * TOK + rbase] = p.u;
      }
    }
  }
}

// ---------------- flash attention v8: 32x32 MFMA, zero-LDS P transform -----
// Block = 128q x 64k, 4 waves = (qg, kh), wave = 64q x 32k (2 q-tiles of 32).
// S^T via mfma_32x32x16 (A=K, B=Q^T): C-layout col=q=lane&31,
// row=key=(reg&3)+8*(reg>>2)+4*(lane>>5). KEY TRICK: bf16-packing the C regs
// yields, directly, a valid PV B-operand under the key permutation
// pi(p) = swap bits 2,3 of p (within each 16-key step). pi is folded into the
// V^T fragment reads (two b64s per frag, same bytes) -> P NEVER touches LDS:
// no Ps buffer (LDS 50->32.5 KB), no round-trip latency.
// Staging, XCD mapping, fixed-max softmax, kh-merge epilogue as v7.
__global__ __launch_bounds__(256, 2) void k_attn(
    const bf16_t* __restrict__ qb, const bf16_t* __restrict__ kb,
    const bf16_t* __restrict__ vT, bf16_t* __restrict__ ao) {
  __shared__ bf16_t Ks[2][64 * 64] __attribute__((aligned(16)));
  __shared__ bf16_t Vs[2][64 * 64] __attribute__((aligned(16)));
  __shared__ float Lm[128];
  const int t = threadIdx.x, lane = t & 63, w = t >> 6;
  const int c32 = lane & 31, h32 = lane >> 5;
  const int qg = w & 1, kh = w >> 1;
  const int h = blockIdx.x & 15;
  const int q0 = (blockIdx.x >> 4) * 128;
  const bf16_t* qh = qb + (size_t)h * TOK * HDIM;
  const bf16_t* khp = kb + (size_t)h * TOK * HDIM;
  const bf16_t* vhp = vT + (size_t)h * HDIM * TOK;

  // Staging source offsets (XOR swizzle on 8-elem chunks folded into the
  // GLOBAL side; LDS side lane-linear as global_load_lds requires).
  const int ksrc = (t >> 3) * HDIM + (((t & 7) ^ ((t >> 3) & 7)) * 8);
  const int vsrc = (t >> 3) * TOK + (((t & 7) ^ ((t >> 3) & 7)) * 8);

  // Q B-fragments for 32x32x16: n=q=lane&31, k(d) = kstep*16 + h32*8 + j.
  bf16x8 qf[2][4];
#pragma unroll
  for (int qt = 0; qt < 2; qt++)
#pragma unroll
    for (int ks = 0; ks < 4; ks++)
      qf[qt][ks] = *(const bf16x8*)&qh[(size_t)(q0 + qg * 64 + qt * 32 + c32) * HDIM + ks * 16 + h32 * 8];

  const floatx4 ZV4 = {0.f, 0.f, 0.f, 0.f};
  floatx16 o[2][2];            // O^T [dt][qt] 32d x 32q tiles (this key-half)
  floatx4 lacc[2] = {ZV4, ZV4};
#pragma unroll
  for (int dt = 0; dt < 2; dt++)
#pragma unroll
    for (int qt = 0; qt < 2; qt++)
#pragma unroll
      for (int i = 0; i < 16; i++) o[dt][qt][i] = 0.f;

  // Prologue: stage tile 0 into buffer 0.
#pragma unroll
  for (int r = 0; r < 2; r++) {
    async_ld16(&khp[(size_t)(r * 32) * HDIM + ksrc], &Ks[0][r * 2048 + t * 8]);
    async_ld16(&vhp[(size_t)(r * 32) * TOK + vsrc], &Vs[0][r * 2048 + t * 8]);
  }

  for (int it = 0; it < TOK / 64; ++it) {
    const int b = it & 1;
    __syncthreads();   // buffer b staged (prefetched a full phase ago)
    if (it + 1 < TOK / 64) {
      const int j1 = (it + 1) * 64;
#pragma unroll
      for (int r = 0; r < 2; r++) {
        async_ld16(&khp[((size_t)j1 + r * 32) * HDIM + ksrc], &Ks[b ^ 1][r * 2048 + t * 8]);
        async_ld16(&vhp[(size_t)(r * 32) * TOK + j1 + vsrc], &Vs[b ^ 1][r * 2048 + t * 8]);
      }
    }

    // ---- S^T = K * Q^T per 32q tile (keys = kh*32 + C-row)
    floatx16 s[2];
#pragma unroll
    for (int i = 0; i < 16; i++) { s[0][i] = 0.f; s[1][i] = 0.f; }
#pragma unroll
    for (int ks = 0; ks < 4; ks++) {
      bf16x8 kf = *(const bf16x8*)&Ks[b][(kh * 32 + c32) * 64 + (((ks * 2 + h32) ^ (c32 & 7)) * 8)];
#pragma unroll
      for (int qt = 0; qt < 2; qt++)
        s[qt] = __builtin_amdgcn_mfma_f32_32x32x16_bf16(kf, qf[qt][ks], s[qt], 0, 0, 0);
    }

    // ---- P = exp2(S) (fixed-max), l partials, bf16 pack (pk IS the B-frag)
    uint32_t pk[2][8];
#pragma unroll
    for (int qt = 0; qt < 2; qt++) {
#pragma unroll
      for (int i = 0; i < 16; i++) s[qt][i] = __builtin_amdgcn_exp2f(s[qt][i]);
#pragma unroll
      for (int i = 0; i < 4; i++)
#pragma unroll
        for (int r = 0; r < 4; r++) lacc[qt][r] += s[qt][i * 4 + r];
#pragma unroll
      for (int i = 0; i < 8; i++) pk[qt][i] = pkbf(s[qt][2 * i], s[qt][2 * i + 1]);
    }

    // ---- O^T += V^T * P : per 16-key step st, pf = pk[4st..4st+3];
    //      vf reads permuted columns pi: keys 4*h32 + (j&3) + 8*(j>>2)
#pragma unroll
    for (int st = 0; st < 2; st++) {
      bf16x8 pf[2];
#pragma unroll
      for (int qt = 0; qt < 2; qt++) {
        union { uint32_t u[4]; bf16x8 v; } pp;
#pragma unroll
        for (int a = 0; a < 4; a++) pp.u[a] = pk[qt][st * 4 + a];
        pf[qt] = pp.v;
      }
      const int cb = kh * 4 + st * 2;
#pragma unroll
      for (int dt = 0; dt < 2; dt++) {
        const int drow = (dt * 32 + c32) * 64;
        union { uint64_t u[2]; bf16x8 v; } vv;
        vv.u[0] = *(const uint64_t*)&Vs[b][drow + ((cb ^ (c32 & 7)) * 8) + 4 * h32];
        vv.u[1] = *(const uint64_t*)&Vs[b][drow + (((cb + 1) ^ (c32 & 7)) * 8) + 4 * h32];
#pragma unroll
        for (int qt = 0; qt < 2; qt++)
          o[dt][qt] = __builtin_amdgcn_mfma_f32_32x32x16_bf16(vv.v, pf[qt], o[dt][qt], 0, 0, 0);
      }
    }
  }

  // ---- epilogue: finish l (rows split over reg,h32 -> one shfl), merge kh.
  float lq[2];
#pragma unroll
  for (int qt = 0; qt < 2; qt++) {
    float l = lacc[qt][0] + lacc[qt][1] + lacc[qt][2] + lacc[qt][3];
    l += __shfl_xor(l, 32, 64);
    lq[qt] = l;
  }
  __syncthreads();
  float* Mrg = (qg == 0) ? (float*)&Ks[0][0] : (float*)&Vs[0][0];  // 64q x 64d
  if (kh == 1) {
#pragma unroll
    for (int qt = 0; qt < 2; qt++) {
#pragma unroll
      for (int dt = 0; dt < 2; dt++)
#pragma unroll
        for (int r = 0; r < 4; r++) {
          floatx4 ov = {o[dt][qt][4 * r], o[dt][qt][4 * r + 1],
                        o[dt][qt][4 * r + 2], o[dt][qt][4 * r + 3]};
          *(floatx4*)&Mrg[(qt * 32 + c32) * 64 + dt * 32 + 8 * r + 4 * h32] = ov;
        }
      if (h32 == 0) Lm[qg * 64 + qt * 32 + c32] = lq[qt];
    }
  }
  __syncthreads();
  if (kh == 0) {
#pragma unroll
    for (int qt = 0; qt < 2; qt++) {
      const float inv = 1.0f / (lq[qt] + Lm[qg * 64 + qt * 32 + c32]);
      const int qrow = q0 + qg * 64 + qt * 32 + c32;
#pragma unroll
      for (int dt = 0; dt < 2; dt++)
#pragma unroll
        for (int r = 0; r < 4; r++) {
          floatx4 ov = *(const floatx4*)&Mrg[(qt * 32 + c32) * 64 + dt * 32 + 8 * r + 4 * h32];
          union { bf16_t b4[4]; uint64_t u; } p;
#pragma unroll
          for (int e = 0; e < 4; e++)
            p.b4[e] = (bf16_t)((o[dt][qt][4 * r + e] + ov[e]) * inv);
          *(uint64_t*)&ao[(size_t)qrow * DIM_ + h * HDIM + dt * 32 + 8 * r + 4 * h32] = p.u;
        }
    }
  }
}

// ---------------- proj GEMM + bias (fp32 out), 64x128 tiles ----------------
__global__ __launch_bounds__(256) void k_proj(
    const bf16_t* __restrict__ A,   // [4096][1024]
    const bf16_t* __restrict__ Bt,  // [1024][1024]
    const float* __restrict__ bias, float* __restrict__ out) {
  constexpr int K = 1024, BK = 32;
  __shared__ bf16_t As[64 * BK] __attribute__((aligned(16)));
  __shared__ bf16_t Bs[128 * BK] __attribute__((aligned(16)));
  const int t = threadIdx.x;
  const int lane = t & 63, w = t >> 6;
  const int lrow = lane & 15, quad = lane >> 4;
  const int m0 = blockIdx.y * 64, n0 = blockIdx.x * 128;
  const int wm = (w >> 1) * 32, wn = (w & 1) * 64;

  const floatx4 ZV = {0.f, 0.f, 0.f, 0.f};
  floatx4 acc[2][4];
#pragma unroll
  for (int i = 0; i < 2; i++)
#pragma unroll
    for (int j = 0; j < 4; j++) acc[i][j] = ZV;

  for (int kt = 0; kt < K; kt += BK) {
    async_ld16(&A[(size_t)(m0 + (t >> 2)) * K + kt + (t & 3) * 8], &As[w * 512]);
#pragma unroll
    for (int r = 0; r < 2; r++) {
      int idx = r * 256 + t;
      async_ld16(&Bt[(size_t)(n0 + (idx >> 2)) * K + kt + (idx & 3) * 8],
                 &Bs[(r * 256 + w * 64) * 8]);
    }
    __syncthreads();
    bf16x8 af[2], bf[4];
#pragma unroll
    for (int i = 0; i < 2; i++)
      af[i] = *(const bf16x8*)&As[(wm + i * 16 + lrow) * BK + quad * 8];
#pragma unroll
    for (int i = 0; i < 4; i++)
      bf[i] = *(const bf16x8*)&Bs[(wn + i * 16 + lrow) * BK + quad * 8];
#pragma unroll
    for (int mi = 0; mi < 2; mi++)
#pragma unroll
      for (int ni = 0; ni < 4; ni++)
        acc[mi][ni] = __builtin_amdgcn_mfma_f32_16x16x32_bf16(af[mi], bf[ni], acc[mi][ni], 0, 0, 0);
    __syncthreads();
  }

  const int c0 = n0 + wn;
#pragma unroll
  for (int ni = 0; ni < 4; ni++) {
    float bv = bias[c0 + ni * 16 + lrow];
#pragma unroll
    for (int mi = 0; mi < 2; mi++)
#pragma unroll
      for (int reg = 0; reg < 4; reg++) {
        int r = m0 + wm + mi * 16 + quad * 4 + reg;
        out[(size_t)r * DIM_ + c0 + ni * 16 + lrow] = acc[mi][ni][reg] + bv;
      }
  }
}

extern "C" void kernel_launch(void* const* d_in, const int* in_sizes, int n_in,
                              void* d_out, int out_size, void* d_ws, size_t ws_size,
                              hipStream_t stream) {
  const float* x      = (const float*)d_in[0];
  const float* cs     = (const float*)d_in[1];
  const float* sn     = (const float*)d_in[2];
  const float* w_qkv  = (const float*)d_in[3];
  const float* b_qkv  = (const float*)d_in[4];
  const float* w_proj = (const float*)d_in[5];
  const float* b_proj = (const float*)d_in[6];
  float* out = (float*)d_out;

  char* ws = (char*)d_ws;
  bf16_t* xb     = (bf16_t*)(ws);
  bf16_t* wqkvT  = (bf16_t*)(ws + 8388608);
  bf16_t* wprojT = (bf16_t*)(ws + 14680064);
  bf16_t* qb     = (bf16_t*)(ws + 16777216);
  bf16_t* kb     = (bf16_t*)(ws + 25165824);
  bf16_t* vT     = (bf16_t*)(ws + 33554432);
  bf16_t* ao     = xb;  // x is dead after k_qkv; reuse its region

  k_prep<<<dim3(8192), dim3(256), 0, stream>>>(x, w_qkv, w_proj, xb, wqkvT, wprojT);
  k_qkv<<<dim3(24, 32), dim3(256), 0, stream>>>(xb, wqkvT, b_qkv, cs, sn, qb, kb, vT);
  k_attn<<<dim3(512), dim3(256), 0, stream>>>(qb, kb, vT, ao);
  k_proj<<<dim3(8, 64), dim3(256), 0, stream>>>(ao, wprojT, b_proj, out);
}